// Round 11
// baseline (208.126 us; speedup 1.0000x reference)
//
#include <hip/hip_runtime.h>

#define L 2048
#define E 128
#define NB 8

typedef float f32x4 __attribute__((ext_vector_type(4)));
typedef short short8 __attribute__((ext_vector_type(8)));
typedef unsigned int u32;

static __device__ inline float bf2f(ushort u) {
  union { float f; u32 i; } v; v.i = ((u32)u) << 16; return v.f;
}
static __device__ inline ushort f2bf(float f) {
  union { float f; u32 i; } v; v.f = f;
  u32 x = v.i;
  return (ushort)((x + 0x7fffu + ((x >> 16) & 1u)) >> 16);  // RTNE
}

// async global->LDS, 16B/lane; lds dest wave-uniform base, HW adds lane*16B
__device__ inline void glds16(const ushort* g, ushort* l) {
  __builtin_amdgcn_global_load_lds(
      (const __attribute__((address_space(1))) u32*)(const void*)g,
      (__attribute__((address_space(3))) u32*)(void*)l, 16, 0, 0);
}

// ---------------------------------------------------------------------------
// prep2 (fused prep + transposes): 64-row x 128-e tiles.
// fp32 Uq/Uid read ONCE -> UqB/UidB/Uidw (row-major), UqT/UidT (transposed
// via LDS), s_id/s_q (8-lane shfl row sums). Kills the separate k_tr2 pass.
// ---------------------------------------------------------------------------
__global__ __launch_bounds__(512) void k_prep2(const float* __restrict__ Uq,
                                               const float* __restrict__ Uid,
                                               const float* __restrict__ Wcw,
                                               ushort* __restrict__ UqB,
                                               ushort* __restrict__ UidB,
                                               ushort* __restrict__ Uidw,
                                               ushort* __restrict__ UqT,
                                               ushort* __restrict__ UidT,
                                               float* __restrict__ s_id,
                                               float* __restrict__ s_q) {
  __shared__ float ldsW[384];
  __shared__ ushort tq[128 * 72];            // 18 KB
  __shared__ ushort td[128 * 72];            // 18 KB
  int t = threadIdx.x;
  if (t < 384) ldsW[t] = bf2f(f2bf(Wcw[t]));
  long r0 = (long)blockIdx.x * 64;           // global row base (never straddles batch)
  int r = t >> 3;                            // 0..63
  int e0 = (t & 7) * 16;                     // 0,16,..,112
  __syncthreads();
  const float* pq = Uq  + (r0 + r) * E + e0;
  const float* pd = Uid + (r0 + r) * E + e0;
  float4 q4[4], d4[4];
  #pragma unroll
  for (int c = 0; c < 4; c++) { q4[c] = *(const float4*)(pq + c * 4); d4[c] = *(const float4*)(pd + c * 4); }
  ushort uqb[16], udb[16], uwb[16];
  float sid = 0.f, sq = 0.f;
  #pragma unroll
  for (int c = 0; c < 4; c++) {
    const float* qf4 = (const float*)&q4[c];
    const float* df4 = (const float*)&d4[c];
    #pragma unroll
    for (int j = 0; j < 4; j++) {
      int k = c * 4 + j;
      ushort qb = f2bf(qf4[j]), db = f2bf(df4[j]);
      float qf = bf2f(qb), df = bf2f(db);
      uqb[k] = qb; udb[k] = db;
      uwb[k] = f2bf(df * ldsW[256 + e0 + k]);
      sid += df * ldsW[e0 + k];
      sq  += qf * ldsW[128 + e0 + k];
    }
  }
  long rb = (r0 + r) * E + e0;
  *(uint4*)&UqB[rb]      = *(const uint4*)&uqb[0];
  *(uint4*)&UqB[rb + 8]  = *(const uint4*)&uqb[8];
  *(uint4*)&UidB[rb]     = *(const uint4*)&udb[0];
  *(uint4*)&UidB[rb + 8] = *(const uint4*)&udb[8];
  *(uint4*)&Uidw[rb]     = *(const uint4*)&uwb[0];
  *(uint4*)&Uidw[rb + 8] = *(const uint4*)&uwb[8];
  #pragma unroll
  for (int off = 4; off >= 1; off >>= 1) {
    sid += __shfl_xor(sid, off, 64);
    sq  += __shfl_xor(sq,  off, 64);
  }
  if ((t & 7) == 0) { s_id[r0 + r] = sid; s_q[r0 + r] = sq; }
  // transpose via LDS
  #pragma unroll
  for (int k = 0; k < 16; k++) {
    tq[(e0 + k) * 72 + r] = uqb[k];
    td[(e0 + k) * 72 + r] = udb[k];
  }
  __syncthreads();
  int e = t >> 2, rs = (t & 3) * 16;
  long b = r0 / L, rl = r0 - b * L;
  long ob = b * E * L + (long)e * L + rl + rs;
  uint4 v0 = *(const uint4*)&tq[e * 72 + rs];
  uint4 v1 = *(const uint4*)&tq[e * 72 + rs + 8];
  *(uint4*)&UqT[ob] = v0; *(uint4*)&UqT[ob + 8] = v1;
  v0 = *(const uint4*)&td[e * 72 + rs];
  v1 = *(const uint4*)&td[e * 72 + rs + 8];
  *(uint4*)&UidT[ob] = v0; *(uint4*)&UidT[ob + 8] = v1;
}

// ---------------------------------------------------------------------------
// maskT: fp32 mask[i][j] -> bf16 maskT[j][i]
// ---------------------------------------------------------------------------
__global__ __launch_bounds__(256) void k_maskT(const float* __restrict__ mask,
                                               ushort* __restrict__ maskT) {
  __shared__ ushort tile[32][33];
  int j0 = blockIdx.x * 32, i0 = blockIdx.y * 32;
  int tx = threadIdx.x, ty = threadIdx.y;
  #pragma unroll
  for (int r = ty; r < 32; r += 8)
    tile[r][tx] = f2bf(mask[(long)(i0 + r) * L + j0 + tx]);
  __syncthreads();
  #pragma unroll
  for (int r = ty; r < 32; r += 8)
    maskT[(long)(j0 + r) * L + i0 + tx] = tile[tx][r];
}

// ---------------------------------------------------------------------------
// scores (512 thr, 128j x 256i tile): E[bz,j,i] = exp(S*maskT), partial
// row-sums -> ps. GEMM: 8 waves (2m x 4n), K=E=128. Epilogue: two 128x128
// half-passes through the swizzled LDS tile.
// ---------------------------------------------------------------------------
__global__ __launch_bounds__(512) void k_scores(const ushort* __restrict__ Uq,
                                                const ushort* __restrict__ Uidw,
                                                const float* __restrict__ s_id,
                                                const float* __restrict__ s_q,
                                                const float* __restrict__ Wcb,
                                                const ushort* __restrict__ maskT,
                                                ushort* __restrict__ St,
                                                float* __restrict__ ps, int b0) {
  __shared__ ushort lds[24576];             // 48KB: A[0..8k) B[8k..24k); tile aliases [0..16k)
  ushort* ldsA = lds;
  ushort* ldsB = lds + 8192;
  int bz = blockIdx.z, b = b0 + bz;
  int m0 = blockIdx.x * 128;   // j
  int n0 = blockIdx.y * 256;   // i
  int tile_i = blockIdx.y;     // 0..7
  const ushort* A = Uq   + (long)b * L * E + (long)m0 * E;
  const ushort* B = Uidw + (long)b * L * E + (long)n0 * E;
  const int t = threadIdx.x, w = t >> 6, lane = t & 63;
  const int mrow = lane & 15, quad = lane >> 4;
  const int lr = lane >> 3;
  const int lc = ((lane & 7) ^ lr) * 8;
  const int mh = (w & 1) * 64;
  const int nh2 = (w >> 1);                 // 0..3 (64-i slab)
  f32x4 acc[4][4] = {};
  for (int k0 = 0; k0 < E; k0 += 64) {
    __syncthreads();
    #pragma unroll
    for (int s = 0; s < 2; s++) {
      int row = w * 16 + s * 8 + lr;        // 0..127, row&7 == lr
      glds16(&A[(long)row * E + k0 + lc], &ldsA[w * 1024 + s * 512]);
    }
    #pragma unroll
    for (int s = 0; s < 4; s++) {
      int row = w * 32 + s * 8 + lr;        // 0..255, row&7 == lr
      glds16(&B[(long)row * E + k0 + lc], &ldsB[w * 2048 + s * 512]);
    }
    __syncthreads();
    #pragma unroll
    for (int kk = 0; kk < 2; kk++) {
      short8 av[4], bv[4];
      #pragma unroll
      for (int mi = 0; mi < 4; mi++)
        av[mi] = *(const short8*)&ldsA[(mh + mi * 16 + mrow) * 64 +
                                       ((kk * 32 + quad * 8) ^ ((mrow & 7) << 3))];
      #pragma unroll
      for (int ni = 0; ni < 4; ni++)
        bv[ni] = *(const short8*)&ldsB[(nh2 * 64 + ni * 16 + mrow) * 64 +
                                       ((kk * 32 + quad * 8) ^ ((mrow & 7) << 3))];
      #pragma unroll
      for (int mi = 0; mi < 4; mi++)
        #pragma unroll
        for (int ni = 0; ni < 4; ni++)
          acc[mi][ni] = __builtin_amdgcn_mfma_f32_16x16x32_bf16(av[mi], bv[ni], acc[mi][ni], 0, 0, 0);
    }
  }
  float bias = bf2f(f2bf(Wcb[0]));
  const int col = mrow;
  for (int h = 0; h < 2; h++) {
    __syncthreads();                        // gemm/prev-half tile reads done
    if ((w >> 2) == h) {                    // waves 4h..4h+3 repack their half
      int nl = (nh2 & 1) * 64;
      float sidv[4];
      #pragma unroll
      for (int ni = 0; ni < 4; ni++)
        sidv[ni] = s_id[b * L + n0 + h * 128 + nl + ni * 16 + col];
      #pragma unroll
      for (int mi = 0; mi < 4; mi++) {
        float sqv[4];
        #pragma unroll
        for (int rg = 0; rg < 4; rg++)
          sqv[rg] = s_q[b * L + m0 + mh + mi * 16 + quad * 4 + rg];
        #pragma unroll
        for (int ni = 0; ni < 4; ni++) {
          int cl = nl + ni * 16 + col;
          #pragma unroll
          for (int rg = 0; rg < 4; rg++) {
            int row = mh + mi * 16 + quad * 4 + rg;
            float v = acc[mi][ni][rg] + sqv[rg] + sidv[ni] + bias;
            lds[row * 128 + (cl ^ ((row & 7) << 3))] = f2bf(v);
          }
        }
      }
    }
    __syncthreads();
    // store pass over the 128x128 half-tile: 512 thr x 32 elems
    ushort oall[32];
    #pragma unroll
    for (int p = 0; p < 4; p++) {
      int r2 = p * 32 + (t >> 4);
      int cu = (t & 15) * 8;
      uint4 sv = *(const uint4*)&lds[r2 * 128 + (cu ^ ((r2 & 7) << 3))];
      int jg = m0 + r2;
      uint4 mv = *(const uint4*)&maskT[(long)jg * L + n0 + h * 128 + cu];
      float lsum = 0.f;
      const ushort* sp = (const ushort*)&sv;
      const ushort* mp = (const ushort*)&mv;
      #pragma unroll
      for (int k = 0; k < 8; k++) {
        float ev = __expf(bf2f(sp[k]) * bf2f(mp[k]));
        oall[p * 8 + k] = f2bf(ev);
        lsum += bf2f(oall[p * 8 + k]);
      }
      #pragma unroll
      for (int off = 8; off >= 1; off >>= 1) lsum += __shfl_xor(lsum, off, 64);
      if ((t & 15) == 0)
        ps[((long)bz * L + jg) * 16 + tile_i * 2 + h] = lsum;
    }
    #pragma unroll
    for (int p = 0; p < 4; p++) {
      int r2 = p * 32 + (t >> 4);
      int cu = (t & 15) * 8;
      int jg = m0 + r2;
      *(uint4*)&St[(long)bz * L * L + (long)jg * L + n0 + h * 128 + cu] = *(const uint4*)&oall[p * 8];
    }
  }
}

// ---------------------------------------------------------------------------
// redstats: fold 16 per-tile partial sums -> lg = 1/rowsum.
// ---------------------------------------------------------------------------
__global__ __launch_bounds__(256) void k_redstats(const float* __restrict__ ps,
                                                  float* __restrict__ lg) {
  int idx = blockIdx.x * 256 + threadIdx.x;   // 0 .. nb*L-1
  const float* psr = ps + (long)idx * 16;
  float s = 0.f;
  #pragma unroll
  for (int k = 0; k < 16; k++) s += psr[k];
  lg[idx] = 1.0f / s;
}

// ---------------------------------------------------------------------------
// 64x64 NT/NT K-loop: BK=64, glds16, XOR chunk-swizzle, DOUBLE-BUF.
// 4 waves, wave tile 32x32 (acc[2][2]). ldsA/ldsB: 2 x 4096 ushorts each.
// ---------------------------------------------------------------------------
__device__ inline void gemm64x64_dbuf(const ushort* __restrict__ A,
                                      const ushort* __restrict__ B,
                                      long ldA, long ldB, int K,
                                      f32x4 acc[2][2],
                                      ushort* ldsA, ushort* ldsB) {
  const int t = threadIdx.x;
  const int w = t >> 6, lane = t & 63;
  const int mrow = lane & 15, quad = lane >> 4;
  const int lr = lane >> 3;
  const int lc = ((lane & 7) ^ lr) * 8;     // pre-swizzled source column
  const int mh = (w & 1) * 32, nh = (w >> 1) * 32;
  #pragma unroll
  for (int s = 0; s < 2; s++) {
    int row = w * 16 + s * 8 + lr;          // row&7 == lr
    glds16(&A[(long)row * ldA + lc], &ldsA[w * 1024 + s * 512]);
    glds16(&B[(long)row * ldB + lc], &ldsB[w * 1024 + s * 512]);
  }
  int cur = 0;
  for (int k0 = 0; k0 < K; k0 += 64) {
    __syncthreads();                        // buf[cur] staged; prev reads done
    int nxt = cur ^ 1;
    if (k0 + 64 < K) {                      // issue next-tile loads NOW
      #pragma unroll
      for (int s = 0; s < 2; s++) {
        int row = w * 16 + s * 8 + lr;
        glds16(&A[(long)row * ldA + k0 + 64 + lc], &ldsA[nxt * 4096 + w * 1024 + s * 512]);
        glds16(&B[(long)row * ldB + k0 + 64 + lc], &ldsB[nxt * 4096 + w * 1024 + s * 512]);
      }
    }
    const ushort* cA = &ldsA[cur * 4096];
    const ushort* cB = &ldsB[cur * 4096];
    #pragma unroll
    for (int kk = 0; kk < 2; kk++) {
      short8 av[2], bv[2];
      #pragma unroll
      for (int mi = 0; mi < 2; mi++)
        av[mi] = *(const short8*)&cA[(mh + mi * 16 + mrow) * 64 +
                                     ((kk * 32 + quad * 8) ^ ((mrow & 7) << 3))];
      #pragma unroll
      for (int ni = 0; ni < 2; ni++)
        bv[ni] = *(const short8*)&cB[(nh + ni * 16 + mrow) * 64 +
                                     ((kk * 32 + quad * 8) ^ ((mrow & 7) << 3))];
      #pragma unroll
      for (int mi = 0; mi < 2; mi++)
        #pragma unroll
        for (int ni = 0; ni < 2; ni++)
          acc[mi][ni] = __builtin_amdgcn_mfma_f32_16x16x32_bf16(av[mi], bv[ni], acc[mi][ni], 0, 0, 0);
    }
    cur = nxt;
  }
}

// ---------------------------------------------------------------------------
// gemm_Tt (64x64): Tt[b,e,j] = lg[j] * sum_i UidT[b,e,i] * E[bz,j,i]
// ---------------------------------------------------------------------------
__global__ __launch_bounds__(256) void k_gemm_Tt(const ushort* __restrict__ UidT,
                                                 const ushort* __restrict__ Et,
                                                 const float* __restrict__ lg,
                                                 ushort* __restrict__ Tt, int b0) {
  __shared__ ushort lds[16384];             // 32KB: A 2x4096 | B 2x4096
  ushort* ldsA = lds;
  ushort* ldsB = lds + 8192;
  int bz = blockIdx.z, b = b0 + bz;
  int e0 = (blockIdx.x & 1) * 64;        // e tile
  int j0 = (blockIdx.x >> 1) * 64;       // j tile
  const ushort* A = UidT + (long)b * E * L + (long)e0 * L;
  const ushort* B = Et   + (long)bz * L * L + (long)j0 * L;
  f32x4 acc[2][2] = {};
  gemm64x64_dbuf(A, B, L, L, L, acc, ldsA, ldsB);
  const int t = threadIdx.x, w = t >> 6, lane = t & 63;
  const int col = lane & 15, quad = lane >> 4;
  const int mh = (w & 1) * 32, nh = (w >> 1) * 32;
  __syncthreads();
  #pragma unroll
  for (int mi = 0; mi < 2; mi++)
    #pragma unroll
    for (int ni = 0; ni < 2; ni++) {
      int cl = nh + ni * 16 + col;
      float sc = lg[(long)bz * L + j0 + cl];
      #pragma unroll
      for (int rg = 0; rg < 4; rg++) {
        int row = mh + mi * 16 + quad * 4 + rg;      // e-local 0..63
        lds[row * 64 + (cl ^ ((row & 7) << 3))] = f2bf(acc[mi][ni][rg] * sc);
      }
    }
  __syncthreads();
  #pragma unroll
  for (int p = 0; p < 2; p++) {
    int r2 = p * 32 + (t >> 3);
    int cu = (t & 7) * 8;
    uint4 v = *(const uint4*)&lds[r2 * 64 + (cu ^ ((r2 & 7) << 3))];
    *(uint4*)&Tt[(long)b * E * L + (long)(e0 + r2) * L + j0 + cu] = v;
  }
}

// ---------------------------------------------------------------------------
// gemm_A (64x128), 512 threads / 8 waves (wave tile 32x32).
// A = Pn[i,j] = E[j,i]*lg[j] staged transposed from Et rows, double-buffered;
// B glds16 double-buffered; reg-prefetch of E two steps ahead.
// ---------------------------------------------------------------------------
__global__ __launch_bounds__(512) void k_gemm_A(const ushort* __restrict__ Et,
                                                const ushort* __restrict__ UqT,
                                                const ushort* __restrict__ Tt,
                                                const ushort* __restrict__ UidB,
                                                const float* __restrict__ lg,
                                                float* __restrict__ out, int b0) {
  __shared__ ushort ldsA[2 * 4608];         // 18 KB, transposed+swizzled A
  __shared__ ushort ldsB[2 * 8192];         // 32 KB
  int bz = blockIdx.z, b = b0 + bz;
  int m0 = blockIdx.x * 64;    // i
  int n0 = blockIdx.y * 128;   // c base: 0 -> Uq, 128 -> T
  const ushort* Eb = Et + (long)bz * L * L + m0;   // row j: Eb[j*L + il]
  const float* lgb = lg + (long)bz * L;
  const ushort* B = (blockIdx.y == 0) ? (UqT + (long)b * E * L)
                                      : (Tt  + (long)b * E * L);
  const int t = threadIdx.x, w = t >> 6, lane = t & 63;
  const int mrow = lane & 15, quad = lane >> 4;
  const int lr = lane >> 3;
  const int lc = ((lane & 7) ^ lr) * 8;
  const int mh = (w & 1) * 32, nh = (w >> 1) * 32;   // 2m x 4n wave grid
  const int jp2 = (t >> 4) * 2;   // j pair base 0..62
  const int ic  = (t & 15) * 4;   // i chunk (4 ushorts)
  f32x4 acc[2][2] = {};
  // prologue: stage k0 = 0 into buf 0
  uint2 q0 = *(const uint2*)&Eb[(long)jp2 * L + ic];
  uint2 q1 = *(const uint2*)&Eb[(long)(jp2 + 1) * L + ic];
  float s0 = lgb[jp2], s1 = lgb[jp2 + 1];
  #pragma unroll
  for (int s = 0; s < 2; s++) {
    int row = w * 16 + s * 8 + lr;          // 0..127, row&7 == lr
    glds16(&B[(long)row * L + lc], &ldsB[w * 1024 + s * 512]);
  }
  {
    const ushort* p0 = (const ushort*)&q0;
    const ushort* p1 = (const ushort*)&q1;
    #pragma unroll
    for (int k = 0; k < 4; k++) {
      u32 pk = (u32)f2bf(bf2f(p0[k]) * s0) |
               ((u32)f2bf(bf2f(p1[k]) * s1) << 16);
      int i = ic + k;
      int cs = jp2 ^ (((i >> 3) & 7) << 3);
      *(u32*)&ldsA[i * 72 + cs] = pk;
    }
  }
  // reg-prefetch k0 = 64
  q0 = *(const uint2*)&Eb[(long)(64 + jp2) * L + ic];
  q1 = *(const uint2*)&Eb[(long)(64 + jp2 + 1) * L + ic];
  s0 = lgb[64 + jp2]; s1 = lgb[64 + jp2 + 1];

  int cur = 0;
  for (int k0 = 0; k0 < L; k0 += 64) {
    __syncthreads();                        // buf[cur] ready; q regs landed
    int nxt = cur ^ 1;
    if (k0 + 64 < L) {
      #pragma unroll
      for (int s = 0; s < 2; s++) {
        int row = w * 16 + s * 8 + lr;
        glds16(&B[(long)row * L + k0 + 64 + lc], &ldsB[nxt * 8192 + w * 1024 + s * 512]);
      }
      const ushort* p0 = (const ushort*)&q0;
      const ushort* p1 = (const ushort*)&q1;
      #pragma unroll
      for (int k = 0; k < 4; k++) {
        u32 pk = (u32)f2bf(bf2f(p0[k]) * s0) |
                 ((u32)f2bf(bf2f(p1[k]) * s1) << 16);
        int i = ic + k;
        int cs = jp2 ^ (((i >> 3) & 7) << 3);
        *(u32*)&ldsA[nxt * 4608 + i * 72 + cs] = pk;
      }
    }
    // reg-prefetch k0+128 (lands during this and next compute phase)
    if (k0 + 128 < L) {
      q0 = *(const uint2*)&Eb[(long)(k0 + 128 + jp2) * L + ic];
      q1 = *(const uint2*)&Eb[(long)(k0 + 128 + jp2 + 1) * L + ic];
      s0 = lgb[k0 + 128 + jp2]; s1 = lgb[k0 + 128 + jp2 + 1];
    }
    const ushort* cA = &ldsA[cur * 4608];
    const ushort* cB = &ldsB[cur * 8192];
    #pragma unroll
    for (int kk = 0; kk < 2; kk++) {
      short8 av[2], bv[2];
      #pragma unroll
      for (int mi = 0; mi < 2; mi++) {
        int i = mh + mi * 16 + mrow;
        av[mi] = *(const short8*)&cA[i * 72 +
                   ((kk * 32 + quad * 8) ^ (((i >> 3) & 7) << 3))];
      }
      #pragma unroll
      for (int ni = 0; ni < 2; ni++)
        bv[ni] = *(const short8*)&cB[(nh + ni * 16 + mrow) * 64 +
                                     ((kk * 32 + quad * 8) ^ ((mrow & 7) << 3))];
      #pragma unroll
      for (int mi = 0; mi < 2; mi++)
        #pragma unroll
        for (int ni = 0; ni < 2; ni++)
          acc[mi][ni] = __builtin_amdgcn_mfma_f32_16x16x32_bf16(av[mi], bv[ni], acc[mi][ni], 0, 0, 0);
    }
    cur = nxt;
  }
  const int col = mrow;
  #pragma unroll
  for (int mi = 0; mi < 2; mi++)
    #pragma unroll
    for (int ni = 0; ni < 2; ni++)
      #pragma unroll
      for (int rg = 0; rg < 4; rg++) {
        int ig = m0 + mh + mi * 16 + quad * 4 + rg;
        int c  = n0 + nh + ni * 16 + col;
        float a = acc[mi][ni][rg];
        float uidf = bf2f(UidB[(long)b * L * E + (long)ig * E + (c & 127)]);
        long ob = ((long)b * L + ig) * 512;
        if (c < 128) {
          out[ob + c]       = uidf;        // Vid identity block
          out[ob + 128 + c] = a;           // A_D2Q
          out[ob + 256 + c] = uidf * a;    // Uid * A_D2Q
        } else {
          out[ob + 256 + c] = uidf * a;    // Uid * A_Q2D
        }
      }
}

// ---------------------------------------------------------------------------
extern "C" void kernel_launch(void* const* d_in, const int* in_sizes, int n_in,
                              void* d_out, int out_size, void* d_ws, size_t ws_size,
                              hipStream_t stream) {
  const float* Uq   = (const float*)d_in[0];
  const float* Uid  = (const float*)d_in[1];
  const float* mask = (const float*)d_in[2];
  const float* Wcw  = (const float*)d_in[3];
  const float* Wcb  = (const float*)d_in[4];
  float* out = (float*)d_out;

  char* ws = (char*)d_ws;
  size_t off = 0;
  auto alloc = [&](size_t bytes) -> void* {
    void* p = ws + off; off += (bytes + 255) & ~(size_t)255; return p;
  };
  const size_t nUb = (size_t)NB * L * E * 2;
  ushort* UqB   = (ushort*)alloc(nUb);
  ushort* UidB  = (ushort*)alloc(nUb);
  ushort* Uidw  = (ushort*)alloc(nUb);
  ushort* UqT   = (ushort*)alloc(nUb);
  ushort* UidT  = (ushort*)alloc(nUb);
  ushort* Tt    = (ushort*)alloc(nUb);
  ushort* maskT = (ushort*)alloc((size_t)L * L * 2);
  float*  s_id  = (float*)alloc((size_t)NB * L * 4);
  float*  s_q   = (float*)alloc((size_t)NB * L * 4);
  float*  lg    = (float*)alloc((size_t)NB * L * 4);
  float*  ps    = (float*)alloc((size_t)NB * L * 16 * 4);
  // chunk: St only: nb_c * 8.4 MB
  const size_t per_batch = (size_t)L * L * 2;
  size_t avail = (ws_size > off + per_batch) ? (ws_size - off) : per_batch;
  int nb_c = (int)(avail / per_batch);
  if (nb_c < 1) nb_c = 1;
  if (nb_c > NB) nb_c = NB;
  ushort* St = (ushort*)(ws + off);                      // holds E = exp(S)

  dim3 tb(32, 8);
  k_prep2<<<NB * L / 64, 512, 0, stream>>>(Uq, Uid, Wcw, UqB, UidB, Uidw, UqT, UidT, s_id, s_q);
  k_maskT<<<dim3(L / 32, L / 32), tb, 0, stream>>>(mask, maskT);

  for (int b0 = 0; b0 < NB; b0 += nb_c) {
    int nb = (NB - b0 < nb_c) ? (NB - b0) : nb_c;
    k_scores<<<dim3(L / 128, L / 256, nb), 512, 0, stream>>>(UqB, Uidw, s_id, s_q, Wcb, maskT, St, ps, b0);
    k_redstats<<<dim3(nb * L / 256), 256, 0, stream>>>(ps, lg);
    k_gemm_Tt<<<dim3(2 * (L / 64), 1, nb), 256, 0, stream>>>(UidT, St, lg, Tt, b0);
    k_gemm_A<<<dim3(L / 64, 2, nb), 512, 0, stream>>>(St, UqT, Tt, UidB, lg, out, b0);
  }
}

// Round 12
// 197.840 us; speedup vs baseline: 1.0520x; 1.0520x over previous
//
#include <hip/hip_runtime.h>

#define L 2048
#define E 128
#define NB 8

typedef float f32x4 __attribute__((ext_vector_type(4)));
typedef short short8 __attribute__((ext_vector_type(8)));
typedef unsigned int u32;

static __device__ inline float bf2f(ushort u) {
  union { float f; u32 i; } v; v.i = ((u32)u) << 16; return v.f;
}
static __device__ inline ushort f2bf(float f) {
  union { float f; u32 i; } v; v.f = f;
  u32 x = v.i;
  return (ushort)((x + 0x7fffu + ((x >> 16) & 1u)) >> 16);  // RTNE
}

// async global->LDS, 16B/lane; lds dest wave-uniform base, HW adds lane*16B
__device__ inline void glds16(const ushort* g, ushort* l) {
  __builtin_amdgcn_global_load_lds(
      (const __attribute__((address_space(1))) u32*)(const void*)g,
      (__attribute__((address_space(3))) u32*)(void*)l, 16, 0, 0);
}

// ---------------------------------------------------------------------------
// prep2 (fused prep + transposes): 64-row x 128-e tiles.
// fp32 Uq/Uid read ONCE -> UqB/UidB/Uidw (row-major), UqT/UidT (transposed
// via LDS), s_id/s_q (8-lane shfl row sums). Kills the separate k_tr2 pass.
// ---------------------------------------------------------------------------
__global__ __launch_bounds__(512) void k_prep2(const float* __restrict__ Uq,
                                               const float* __restrict__ Uid,
                                               const float* __restrict__ Wcw,
                                               ushort* __restrict__ UqB,
                                               ushort* __restrict__ UidB,
                                               ushort* __restrict__ Uidw,
                                               ushort* __restrict__ UqT,
                                               ushort* __restrict__ UidT,
                                               float* __restrict__ s_id,
                                               float* __restrict__ s_q) {
  __shared__ float ldsW[384];
  __shared__ ushort tq[128 * 72];            // 18 KB
  __shared__ ushort td[128 * 72];            // 18 KB
  int t = threadIdx.x;
  if (t < 384) ldsW[t] = bf2f(f2bf(Wcw[t]));
  long r0 = (long)blockIdx.x * 64;           // global row base (never straddles batch)
  int r = t >> 3;                            // 0..63
  int e0 = (t & 7) * 16;                     // 0,16,..,112
  __syncthreads();
  const float* pq = Uq  + (r0 + r) * E + e0;
  const float* pd = Uid + (r0 + r) * E + e0;
  float4 q4[4], d4[4];
  #pragma unroll
  for (int c = 0; c < 4; c++) { q4[c] = *(const float4*)(pq + c * 4); d4[c] = *(const float4*)(pd + c * 4); }
  ushort uqb[16], udb[16], uwb[16];
  float sid = 0.f, sq = 0.f;
  #pragma unroll
  for (int c = 0; c < 4; c++) {
    const float* qf4 = (const float*)&q4[c];
    const float* df4 = (const float*)&d4[c];
    #pragma unroll
    for (int j = 0; j < 4; j++) {
      int k = c * 4 + j;
      ushort qb = f2bf(qf4[j]), db = f2bf(df4[j]);
      float qf = bf2f(qb), df = bf2f(db);
      uqb[k] = qb; udb[k] = db;
      uwb[k] = f2bf(df * ldsW[256 + e0 + k]);
      sid += df * ldsW[e0 + k];
      sq  += qf * ldsW[128 + e0 + k];
    }
  }
  long rb = (r0 + r) * E + e0;
  *(uint4*)&UqB[rb]      = *(const uint4*)&uqb[0];
  *(uint4*)&UqB[rb + 8]  = *(const uint4*)&uqb[8];
  *(uint4*)&UidB[rb]     = *(const uint4*)&udb[0];
  *(uint4*)&UidB[rb + 8] = *(const uint4*)&udb[8];
  *(uint4*)&Uidw[rb]     = *(const uint4*)&uwb[0];
  *(uint4*)&Uidw[rb + 8] = *(const uint4*)&uwb[8];
  #pragma unroll
  for (int off = 4; off >= 1; off >>= 1) {
    sid += __shfl_xor(sid, off, 64);
    sq  += __shfl_xor(sq,  off, 64);
  }
  if ((t & 7) == 0) { s_id[r0 + r] = sid; s_q[r0 + r] = sq; }
  // transpose via LDS
  #pragma unroll
  for (int k = 0; k < 16; k++) {
    tq[(e0 + k) * 72 + r] = uqb[k];
    td[(e0 + k) * 72 + r] = udb[k];
  }
  __syncthreads();
  int e = t >> 2, rs = (t & 3) * 16;
  long b = r0 / L, rl = r0 - b * L;
  long ob = b * E * L + (long)e * L + rl + rs;
  uint4 v0 = *(const uint4*)&tq[e * 72 + rs];
  uint4 v1 = *(const uint4*)&tq[e * 72 + rs + 8];
  *(uint4*)&UqT[ob] = v0; *(uint4*)&UqT[ob + 8] = v1;
  v0 = *(const uint4*)&td[e * 72 + rs];
  v1 = *(const uint4*)&td[e * 72 + rs + 8];
  *(uint4*)&UidT[ob] = v0; *(uint4*)&UidT[ob + 8] = v1;
}

// ---------------------------------------------------------------------------
// maskT: fp32 mask[i][j] -> bf16 maskT[j][i]
// ---------------------------------------------------------------------------
__global__ __launch_bounds__(256) void k_maskT(const float* __restrict__ mask,
                                               ushort* __restrict__ maskT) {
  __shared__ ushort tile[32][33];
  int j0 = blockIdx.x * 32, i0 = blockIdx.y * 32;
  int tx = threadIdx.x, ty = threadIdx.y;
  #pragma unroll
  for (int r = ty; r < 32; r += 8)
    tile[r][tx] = f2bf(mask[(long)(i0 + r) * L + j0 + tx]);
  __syncthreads();
  #pragma unroll
  for (int r = ty; r < 32; r += 8)
    maskT[(long)(j0 + r) * L + i0 + tx] = tile[tx][r];
}

// ---------------------------------------------------------------------------
// 128x128 NT/NT K-loop: BK=64, glds16, XOR chunk-swizzle, SINGLE-buffered.
// (k_scores is occupancy-bound: 32KB -> 5 blocks/CU. Do not dbuf — r3 lesson)
// ---------------------------------------------------------------------------
__device__ inline void gemm128_loop(const ushort* __restrict__ A,
                                    const ushort* __restrict__ B,
                                    long ldA, long ldB, int K,
                                    f32x4 acc[4][4],
                                    ushort* ldsA, ushort* ldsB) {
  const int t = threadIdx.x;
  const int w = t >> 6, lane = t & 63;
  const int mrow = lane & 15, quad = lane >> 4;
  const int lr = lane >> 3;
  const int lc = ((lane & 7) ^ lr) * 8;     // pre-swizzled source column
  const int mh = (w & 1) * 64, nh = (w >> 1) * 64;
  for (int k0 = 0; k0 < K; k0 += 64) {
    __syncthreads();
    #pragma unroll
    for (int s = 0; s < 4; s++) {
      int row = w * 32 + s * 8 + lr;        // row&7 == lr
      glds16(&A[(long)row * ldA + k0 + lc], &ldsA[w * 2048 + s * 512]);
      glds16(&B[(long)row * ldB + k0 + lc], &ldsB[w * 2048 + s * 512]);
    }
    __syncthreads();
    #pragma unroll
    for (int kk = 0; kk < 2; kk++) {
      short8 av[4], bv[4];
      #pragma unroll
      for (int mi = 0; mi < 4; mi++)
        av[mi] = *(const short8*)&ldsA[(mh + mi * 16 + mrow) * 64 +
                                       ((kk * 32 + quad * 8) ^ ((mrow & 7) << 3))];
      #pragma unroll
      for (int ni = 0; ni < 4; ni++)
        bv[ni] = *(const short8*)&ldsB[(nh + ni * 16 + mrow) * 64 +
                                       ((kk * 32 + quad * 8) ^ ((mrow & 7) << 3))];
      #pragma unroll
      for (int mi = 0; mi < 4; mi++)
        #pragma unroll
        for (int ni = 0; ni < 4; ni++)
          acc[mi][ni] = __builtin_amdgcn_mfma_f32_16x16x32_bf16(av[mi], bv[ni], acc[mi][ni], 0, 0, 0);
    }
  }
}

// ---------------------------------------------------------------------------
// scores (r10-proven, 256 thr): E[bz,j,i] = exp((dot+sq+sid+bias)*maskT).
// Partial row-sums of E -> ps. Epilogue split in two passes so the 64 exp
// chains overlap and the 8 St stores issue back-to-back.
// ---------------------------------------------------------------------------
__global__ __launch_bounds__(256) void k_scores(const ushort* __restrict__ Uq,
                                                const ushort* __restrict__ Uidw,
                                                const float* __restrict__ s_id,
                                                const float* __restrict__ s_q,
                                                const float* __restrict__ Wcb,
                                                const ushort* __restrict__ maskT,
                                                ushort* __restrict__ St,
                                                float* __restrict__ ps, int b0) {
  __shared__ ushort lds[16384];             // 32KB: gemm A|B, then S-tile
  ushort* ldsA = lds;
  ushort* ldsB = lds + 8192;
  int bz = blockIdx.z, b = b0 + bz;
  int m0 = blockIdx.x * 128;   // j
  int n0 = blockIdx.y * 128;   // i
  int tile_i = blockIdx.y;
  const ushort* A = Uq   + (long)b * L * E + (long)m0 * E;
  const ushort* B = Uidw + (long)b * L * E + (long)n0 * E;
  f32x4 acc[4][4] = {};
  gemm128_loop(A, B, E, E, E, acc, ldsA, ldsB);
  float bias = bf2f(f2bf(Wcb[0]));
  const int t = threadIdx.x, w = t >> 6, lane = t & 63;
  const int col = lane & 15, quad = lane >> 4;
  const int mh = (w & 1) * 64, nh = (w >> 1) * 64;

  __syncthreads();                          // done with gemm LDS
  float sidv[4];
  #pragma unroll
  for (int ni = 0; ni < 4; ni++)
    sidv[ni] = s_id[b * L + n0 + nh + ni * 16 + col];
  #pragma unroll
  for (int mi = 0; mi < 4; mi++) {
    float sqv[4];
    #pragma unroll
    for (int rg = 0; rg < 4; rg++)
      sqv[rg] = s_q[b * L + m0 + mh + mi * 16 + quad * 4 + rg];
    #pragma unroll
    for (int ni = 0; ni < 4; ni++) {
      int cl = nh + ni * 16 + col;
      #pragma unroll
      for (int rg = 0; rg < 4; rg++) {
        int row = mh + mi * 16 + quad * 4 + rg;
        float v = acc[mi][ni][rg] + sqv[rg] + sidv[ni] + bias;
        lds[row * 128 + (cl ^ ((row & 7) << 3))] = f2bf(v);
      }
    }
  }
  __syncthreads();
  ushort oall[64];
  // pass 1: exp + stats (all chains independent, overlap freely)
  #pragma unroll
  for (int p = 0; p < 8; p++) {
    int r2 = p * 16 + (t >> 4);
    int cu = (t & 15) * 8;
    uint4 sv = *(const uint4*)&lds[r2 * 128 + (cu ^ ((r2 & 7) << 3))];
    int jg = m0 + r2;
    uint4 mv = *(const uint4*)&maskT[(long)jg * L + n0 + cu];
    float lsum = 0.f;
    const ushort* sp = (const ushort*)&sv;
    const ushort* mp = (const ushort*)&mv;
    #pragma unroll
    for (int k = 0; k < 8; k++) {
      float ev = __expf(bf2f(sp[k]) * bf2f(mp[k]));
      oall[p * 8 + k] = f2bf(ev);
      lsum += bf2f(oall[p * 8 + k]);        // sum of stored bf16 E values
    }
    #pragma unroll
    for (int off = 8; off >= 1; off >>= 1) lsum += __shfl_xor(lsum, off, 64);
    if ((t & 15) == 0) {
      ps[((long)bz * L + jg) * 16 + tile_i] = lsum;
    }
  }
  // pass 2: independent coalesced stores
  #pragma unroll
  for (int p = 0; p < 8; p++) {
    int r2 = p * 16 + (t >> 4);
    int cu = (t & 15) * 8;
    int jg = m0 + r2;
    *(uint4*)&St[(long)bz * L * L + (long)jg * L + n0 + cu] = *(const uint4*)&oall[p * 8];
  }
}

// ---------------------------------------------------------------------------
// redstats: fold 16 per-tile partial sums -> lg = 1/rowsum.
// ---------------------------------------------------------------------------
__global__ __launch_bounds__(256) void k_redstats(const float* __restrict__ ps,
                                                  float* __restrict__ lg) {
  int idx = blockIdx.x * 256 + threadIdx.x;   // 0 .. nb*L-1
  const float* psr = ps + (long)idx * 16;
  float s = 0.f;
  #pragma unroll
  for (int k = 0; k < 16; k++) s += psr[k];
  lg[idx] = 1.0f / s;
}

// ---------------------------------------------------------------------------
// 64x64 NT/NT K-loop: BK=64, glds16, XOR chunk-swizzle, DOUBLE-BUF.
// 4 waves, wave tile 32x32 (acc[2][2]). ldsA/ldsB: 2 x 4096 ushorts each.
// ---------------------------------------------------------------------------
__device__ inline void gemm64x64_dbuf(const ushort* __restrict__ A,
                                      const ushort* __restrict__ B,
                                      long ldA, long ldB, int K,
                                      f32x4 acc[2][2],
                                      ushort* ldsA, ushort* ldsB) {
  const int t = threadIdx.x;
  const int w = t >> 6, lane = t & 63;
  const int mrow = lane & 15, quad = lane >> 4;
  const int lr = lane >> 3;
  const int lc = ((lane & 7) ^ lr) * 8;     // pre-swizzled source column
  const int mh = (w & 1) * 32, nh = (w >> 1) * 32;
  #pragma unroll
  for (int s = 0; s < 2; s++) {
    int row = w * 16 + s * 8 + lr;          // row&7 == lr
    glds16(&A[(long)row * ldA + lc], &ldsA[w * 1024 + s * 512]);
    glds16(&B[(long)row * ldB + lc], &ldsB[w * 1024 + s * 512]);
  }
  int cur = 0;
  for (int k0 = 0; k0 < K; k0 += 64) {
    __syncthreads();                        // buf[cur] staged; prev reads done
    int nxt = cur ^ 1;
    if (k0 + 64 < K) {                      // issue next-tile loads NOW
      #pragma unroll
      for (int s = 0; s < 2; s++) {
        int row = w * 16 + s * 8 + lr;
        glds16(&A[(long)row * ldA + k0 + 64 + lc], &ldsA[nxt * 4096 + w * 1024 + s * 512]);
        glds16(&B[(long)row * ldB + k0 + 64 + lc], &ldsB[nxt * 4096 + w * 1024 + s * 512]);
      }
    }
    const ushort* cA = &ldsA[cur * 4096];
    const ushort* cB = &ldsB[cur * 4096];
    #pragma unroll
    for (int kk = 0; kk < 2; kk++) {
      short8 av[2], bv[2];
      #pragma unroll
      for (int mi = 0; mi < 2; mi++)
        av[mi] = *(const short8*)&cA[(mh + mi * 16 + mrow) * 64 +
                                     ((kk * 32 + quad * 8) ^ ((mrow & 7) << 3))];
      #pragma unroll
      for (int ni = 0; ni < 2; ni++)
        bv[ni] = *(const short8*)&cB[(nh + ni * 16 + mrow) * 64 +
                                     ((kk * 32 + quad * 8) ^ ((mrow & 7) << 3))];
      #pragma unroll
      for (int mi = 0; mi < 2; mi++)
        #pragma unroll
        for (int ni = 0; ni < 2; ni++)
          acc[mi][ni] = __builtin_amdgcn_mfma_f32_16x16x32_bf16(av[mi], bv[ni], acc[mi][ni], 0, 0, 0);
    }
    cur = nxt;
  }
}

// ---------------------------------------------------------------------------
// gemm_Tt (64x64): Tt[b,e,j] = lg[j] * sum_i UidT[b,e,i] * E[bz,j,i]
// ---------------------------------------------------------------------------
__global__ __launch_bounds__(256) void k_gemm_Tt(const ushort* __restrict__ UidT,
                                                 const ushort* __restrict__ Et,
                                                 const float* __restrict__ lg,
                                                 ushort* __restrict__ Tt, int b0) {
  __shared__ ushort lds[16384];             // 32KB: A 2x4096 | B 2x4096
  ushort* ldsA = lds;
  ushort* ldsB = lds + 8192;
  int bz = blockIdx.z, b = b0 + bz;
  int e0 = (blockIdx.x & 1) * 64;        // e tile
  int j0 = (blockIdx.x >> 1) * 64;       // j tile
  const ushort* A = UidT + (long)b * E * L + (long)e0 * L;
  const ushort* B = Et   + (long)bz * L * L + (long)j0 * L;
  f32x4 acc[2][2] = {};
  gemm64x64_dbuf(A, B, L, L, L, acc, ldsA, ldsB);
  const int t = threadIdx.x, w = t >> 6, lane = t & 63;
  const int col = lane & 15, quad = lane >> 4;
  const int mh = (w & 1) * 32, nh = (w >> 1) * 32;
  __syncthreads();
  #pragma unroll
  for (int mi = 0; mi < 2; mi++)
    #pragma unroll
    for (int ni = 0; ni < 2; ni++) {
      int cl = nh + ni * 16 + col;
      float sc = lg[(long)bz * L + j0 + cl];
      #pragma unroll
      for (int rg = 0; rg < 4; rg++) {
        int row = mh + mi * 16 + quad * 4 + rg;      // e-local 0..63
        lds[row * 64 + (cl ^ ((row & 7) << 3))] = f2bf(acc[mi][ni][rg] * sc);
      }
    }
  __syncthreads();
  #pragma unroll
  for (int p = 0; p < 2; p++) {
    int r2 = p * 32 + (t >> 3);
    int cu = (t & 7) * 8;
    uint4 v = *(const uint4*)&lds[r2 * 64 + (cu ^ ((r2 & 7) << 3))];
    *(uint4*)&Tt[(long)b * E * L + (long)(e0 + r2) * L + j0 + cu] = v;
  }
}

// ---------------------------------------------------------------------------
// gemm_A (64x128), 512 threads / 8 waves (wave tile 32x32).
// A = Pn[i,j] = E[j,i]*lg[j] staged transposed from Et rows, double-buffered;
// B glds16 double-buffered; reg-prefetch of E two steps ahead.
// ---------------------------------------------------------------------------
__global__ __launch_bounds__(512) void k_gemm_A(const ushort* __restrict__ Et,
                                                const ushort* __restrict__ UqT,
                                                const ushort* __restrict__ Tt,
                                                const ushort* __restrict__ UidB,
                                                const float* __restrict__ lg,
                                                float* __restrict__ out, int b0) {
  __shared__ ushort ldsA[2 * 4608];         // 18 KB, transposed+swizzled A
  __shared__ ushort ldsB[2 * 8192];         // 32 KB
  int bz = blockIdx.z, b = b0 + bz;
  int m0 = blockIdx.x * 64;    // i
  int n0 = blockIdx.y * 128;   // c base: 0 -> Uq, 128 -> T
  const ushort* Eb = Et + (long)bz * L * L + m0;   // row j: Eb[j*L + il]
  const float* lgb = lg + (long)bz * L;
  const ushort* B = (blockIdx.y == 0) ? (UqT + (long)b * E * L)
                                      : (Tt  + (long)b * E * L);
  const int t = threadIdx.x, w = t >> 6, lane = t & 63;
  const int mrow = lane & 15, quad = lane >> 4;
  const int lr = lane >> 3;
  const int lc = ((lane & 7) ^ lr) * 8;
  const int mh = (w & 1) * 32, nh = (w >> 1) * 32;   // 2m x 4n wave grid
  const int jp2 = (t >> 4) * 2;   // j pair base 0..62
  const int ic  = (t & 15) * 4;   // i chunk (4 ushorts)
  f32x4 acc[2][2] = {};
  // prologue: stage k0 = 0 into buf 0
  uint2 q0 = *(const uint2*)&Eb[(long)jp2 * L + ic];
  uint2 q1 = *(const uint2*)&Eb[(long)(jp2 + 1) * L + ic];
  float s0 = lgb[jp2], s1 = lgb[jp2 + 1];
  #pragma unroll
  for (int s = 0; s < 2; s++) {
    int row = w * 16 + s * 8 + lr;          // 0..127, row&7 == lr
    glds16(&B[(long)row * L + lc], &ldsB[w * 1024 + s * 512]);
  }
  {
    const ushort* p0 = (const ushort*)&q0;
    const ushort* p1 = (const ushort*)&q1;
    #pragma unroll
    for (int k = 0; k < 4; k++) {
      u32 pk = (u32)f2bf(bf2f(p0[k]) * s0) |
               ((u32)f2bf(bf2f(p1[k]) * s1) << 16);
      int i = ic + k;
      int cs = jp2 ^ (((i >> 3) & 7) << 3);
      *(u32*)&ldsA[i * 72 + cs] = pk;
    }
  }
  // reg-prefetch k0 = 64
  q0 = *(const uint2*)&Eb[(long)(64 + jp2) * L + ic];
  q1 = *(const uint2*)&Eb[(long)(64 + jp2 + 1) * L + ic];
  s0 = lgb[64 + jp2]; s1 = lgb[64 + jp2 + 1];

  int cur = 0;
  for (int k0 = 0; k0 < L; k0 += 64) {
    __syncthreads();                        // buf[cur] ready; q regs landed
    int nxt = cur ^ 1;
    if (k0 + 64 < L) {
      #pragma unroll
      for (int s = 0; s < 2; s++) {
        int row = w * 16 + s * 8 + lr;
        glds16(&B[(long)row * L + k0 + 64 + lc], &ldsB[nxt * 8192 + w * 1024 + s * 512]);
      }
      const ushort* p0 = (const ushort*)&q0;
      const ushort* p1 = (const ushort*)&q1;
      #pragma unroll
      for (int k = 0; k < 4; k++) {
        u32 pk = (u32)f2bf(bf2f(p0[k]) * s0) |
                 ((u32)f2bf(bf2f(p1[k]) * s1) << 16);
        int i = ic + k;
        int cs = jp2 ^ (((i >> 3) & 7) << 3);
        *(u32*)&ldsA[nxt * 4608 + i * 72 + cs] = pk;
      }
    }
    // reg-prefetch k0+128 (lands during this and next compute phase)
    if (k0 + 128 < L) {
      q0 = *(const uint2*)&Eb[(long)(k0 + 128 + jp2) * L + ic];
      q1 = *(const uint2*)&Eb[(long)(k0 + 128 + jp2 + 1) * L + ic];
      s0 = lgb[k0 + 128 + jp2]; s1 = lgb[k0 + 128 + jp2 + 1];
    }
    const ushort* cA = &ldsA[cur * 4608];
    const ushort* cB = &ldsB[cur * 8192];
    #pragma unroll
    for (int kk = 0; kk < 2; kk++) {
      short8 av[2], bv[2];
      #pragma unroll
      for (int mi = 0; mi < 2; mi++) {
        int i = mh + mi * 16 + mrow;
        av[mi] = *(const short8*)&cA[i * 72 +
                   ((kk * 32 + quad * 8) ^ (((i >> 3) & 7) << 3))];
      }
      #pragma unroll
      for (int ni = 0; ni < 2; ni++)
        bv[ni] = *(const short8*)&cB[(nh + ni * 16 + mrow) * 64 +
                                     ((kk * 32 + quad * 8) ^ ((mrow & 7) << 3))];
      #pragma unroll
      for (int mi = 0; mi < 2; mi++)
        #pragma unroll
        for (int ni = 0; ni < 2; ni++)
          acc[mi][ni] = __builtin_amdgcn_mfma_f32_16x16x32_bf16(av[mi], bv[ni], acc[mi][ni], 0, 0, 0);
    }
    cur = nxt;
  }
  const int col = mrow;
  #pragma unroll
  for (int mi = 0; mi < 2; mi++)
    #pragma unroll
    for (int ni = 0; ni < 2; ni++)
      #pragma unroll
      for (int rg = 0; rg < 4; rg++) {
        int ig = m0 + mh + mi * 16 + quad * 4 + rg;
        int c  = n0 + nh + ni * 16 + col;
        float a = acc[mi][ni][rg];
        float uidf = bf2f(UidB[(long)b * L * E + (long)ig * E + (c & 127)]);
        long ob = ((long)b * L + ig) * 512;
        if (c < 128) {
          out[ob + c]       = uidf;        // Vid identity block
          out[ob + 128 + c] = a;           // A_D2Q
          out[ob + 256 + c] = uidf * a;    // Uid * A_D2Q
        } else {
          out[ob + 256 + c] = uidf * a;    // Uid * A_Q2D
        }
      }
}

// ---------------------------------------------------------------------------
extern "C" void kernel_launch(void* const* d_in, const int* in_sizes, int n_in,
                              void* d_out, int out_size, void* d_ws, size_t ws_size,
                              hipStream_t stream) {
  const float* Uq   = (const float*)d_in[0];
  const float* Uid  = (const float*)d_in[1];
  const float* mask = (const float*)d_in[2];
  const float* Wcw  = (const float*)d_in[3];
  const float* Wcb  = (const float*)d_in[4];
  float* out = (float*)d_out;

  char* ws = (char*)d_ws;
  size_t off = 0;
  auto alloc = [&](size_t bytes) -> void* {
    void* p = ws + off; off += (bytes + 255) & ~(size_t)255; return p;
  };
  const size_t nUb = (size_t)NB * L * E * 2;
  ushort* UqB   = (ushort*)alloc(nUb);
  ushort* UidB  = (ushort*)alloc(nUb);
  ushort* Uidw  = (ushort*)alloc(nUb);
  ushort* UqT   = (ushort*)alloc(nUb);
  ushort* UidT  = (ushort*)alloc(nUb);
  ushort* Tt    = (ushort*)alloc(nUb);
  ushort* maskT = (ushort*)alloc((size_t)L * L * 2);
  float*  s_id  = (float*)alloc((size_t)NB * L * 4);
  float*  s_q   = (float*)alloc((size_t)NB * L * 4);
  float*  lg    = (float*)alloc((size_t)NB * L * 4);
  float*  ps    = (float*)alloc((size_t)NB * L * 16 * 4);
  // chunk: St only: nb_c * 8.4 MB
  const size_t per_batch = (size_t)L * L * 2;
  size_t avail = (ws_size > off + per_batch) ? (ws_size - off) : per_batch;
  int nb_c = (int)(avail / per_batch);
  if (nb_c < 1) nb_c = 1;
  if (nb_c > NB) nb_c = NB;
  ushort* St = (ushort*)(ws + off);                      // holds E = exp(S)

  dim3 tb(32, 8);
  k_prep2<<<NB * L / 64, 512, 0, stream>>>(Uq, Uid, Wcw, UqB, UidB, Uidw, UqT, UidT, s_id, s_q);
  k_maskT<<<dim3(L / 32, L / 32), tb, 0, stream>>>(mask, maskT);

  for (int b0 = 0; b0 < NB; b0 += nb_c) {
    int nb = (NB - b0 < nb_c) ? (NB - b0) : nb_c;
    k_scores<<<dim3(L / 128, L / 128, nb), 256, 0, stream>>>(UqB, Uidw, s_id, s_q, Wcb, maskT, St, ps, b0);
    k_redstats<<<dim3(nb * L / 256), 256, 0, stream>>>(ps, lg);
    k_gemm_Tt<<<dim3(2 * (L / 64), 1, nb), 256, 0, stream>>>(UidT, St, lg, Tt, b0);
    k_gemm_A<<<dim3(L / 64, 2, nb), 512, 0, stream>>>(St, UqT, Tt, UidB, lg, out, b0);
  }
}

// Round 13
// 196.048 us; speedup vs baseline: 1.0616x; 1.0091x over previous
//
#include <hip/hip_runtime.h>

#define L 2048
#define E 128
#define NB 8

typedef float f32x4 __attribute__((ext_vector_type(4)));
typedef short short8 __attribute__((ext_vector_type(8)));
typedef unsigned int u32;

static __device__ inline float bf2f(ushort u) {
  union { float f; u32 i; } v; v.i = ((u32)u) << 16; return v.f;
}
static __device__ inline ushort f2bf(float f) {
  union { float f; u32 i; } v; v.f = f;
  u32 x = v.i;
  return (ushort)((x + 0x7fffu + ((x >> 16) & 1u)) >> 16);  // RTNE
}

// async global->LDS, 16B/lane; lds dest wave-uniform base, HW adds lane*16B
__device__ inline void glds16(const ushort* g, ushort* l) {
  __builtin_amdgcn_global_load_lds(
      (const __attribute__((address_space(1))) u32*)(const void*)g,
      (__attribute__((address_space(3))) u32*)(void*)l, 16, 0, 0);
}

// ---------------------------------------------------------------------------
// prep2 (fused prep + transposes): 64-row x 128-e tiles.
// ---------------------------------------------------------------------------
__global__ __launch_bounds__(512) void k_prep2(const float* __restrict__ Uq,
                                               const float* __restrict__ Uid,
                                               const float* __restrict__ Wcw,
                                               ushort* __restrict__ UqB,
                                               ushort* __restrict__ UidB,
                                               ushort* __restrict__ Uidw,
                                               ushort* __restrict__ UqT,
                                               ushort* __restrict__ UidT,
                                               float* __restrict__ s_id,
                                               float* __restrict__ s_q) {
  __shared__ float ldsW[384];
  __shared__ ushort tq[128 * 72];            // 18 KB
  __shared__ ushort td[128 * 72];            // 18 KB
  int t = threadIdx.x;
  if (t < 384) ldsW[t] = bf2f(f2bf(Wcw[t]));
  long r0 = (long)blockIdx.x * 64;           // global row base (never straddles batch)
  int r = t >> 3;                            // 0..63
  int e0 = (t & 7) * 16;                     // 0,16,..,112
  __syncthreads();
  const float* pq = Uq  + (r0 + r) * E + e0;
  const float* pd = Uid + (r0 + r) * E + e0;
  float4 q4[4], d4[4];
  #pragma unroll
  for (int c = 0; c < 4; c++) { q4[c] = *(const float4*)(pq + c * 4); d4[c] = *(const float4*)(pd + c * 4); }
  ushort uqb[16], udb[16], uwb[16];
  float sid = 0.f, sq = 0.f;
  #pragma unroll
  for (int c = 0; c < 4; c++) {
    const float* qf4 = (const float*)&q4[c];
    const float* df4 = (const float*)&d4[c];
    #pragma unroll
    for (int j = 0; j < 4; j++) {
      int k = c * 4 + j;
      ushort qb = f2bf(qf4[j]), db = f2bf(df4[j]);
      float qf = bf2f(qb), df = bf2f(db);
      uqb[k] = qb; udb[k] = db;
      uwb[k] = f2bf(df * ldsW[256 + e0 + k]);
      sid += df * ldsW[e0 + k];
      sq  += qf * ldsW[128 + e0 + k];
    }
  }
  long rb = (r0 + r) * E + e0;
  *(uint4*)&UqB[rb]      = *(const uint4*)&uqb[0];
  *(uint4*)&UqB[rb + 8]  = *(const uint4*)&uqb[8];
  *(uint4*)&UidB[rb]     = *(const uint4*)&udb[0];
  *(uint4*)&UidB[rb + 8] = *(const uint4*)&udb[8];
  *(uint4*)&Uidw[rb]     = *(const uint4*)&uwb[0];
  *(uint4*)&Uidw[rb + 8] = *(const uint4*)&uwb[8];
  #pragma unroll
  for (int off = 4; off >= 1; off >>= 1) {
    sid += __shfl_xor(sid, off, 64);
    sq  += __shfl_xor(sq,  off, 64);
  }
  if ((t & 7) == 0) { s_id[r0 + r] = sid; s_q[r0 + r] = sq; }
  // transpose via LDS
  #pragma unroll
  for (int k = 0; k < 16; k++) {
    tq[(e0 + k) * 72 + r] = uqb[k];
    td[(e0 + k) * 72 + r] = udb[k];
  }
  __syncthreads();
  int e = t >> 2, rs = (t & 3) * 16;
  long b = r0 / L, rl = r0 - b * L;
  long ob = b * E * L + (long)e * L + rl + rs;
  uint4 v0 = *(const uint4*)&tq[e * 72 + rs];
  uint4 v1 = *(const uint4*)&tq[e * 72 + rs + 8];
  *(uint4*)&UqT[ob] = v0; *(uint4*)&UqT[ob + 8] = v1;
  v0 = *(const uint4*)&td[e * 72 + rs];
  v1 = *(const uint4*)&td[e * 72 + rs + 8];
  *(uint4*)&UidT[ob] = v0; *(uint4*)&UidT[ob + 8] = v1;
}

// ---------------------------------------------------------------------------
// maskT: fp32 mask[i][j] -> bf16 maskT[j][i]
// ---------------------------------------------------------------------------
__global__ __launch_bounds__(256) void k_maskT(const float* __restrict__ mask,
                                               ushort* __restrict__ maskT) {
  __shared__ ushort tile[32][33];
  int j0 = blockIdx.x * 32, i0 = blockIdx.y * 32;
  int tx = threadIdx.x, ty = threadIdx.y;
  #pragma unroll
  for (int r = ty; r < 32; r += 8)
    tile[r][tx] = f2bf(mask[(long)(i0 + r) * L + j0 + tx]);
  __syncthreads();
  #pragma unroll
  for (int r = ty; r < 32; r += 8)
    maskT[(long)(j0 + r) * L + i0 + tx] = tile[tx][r];
}

// ---------------------------------------------------------------------------
// 128x128 NT/NT K-loop: BK=64, glds16, XOR chunk-swizzle, SINGLE-buffered.
// ---------------------------------------------------------------------------
__device__ inline void gemm128_loop(const ushort* __restrict__ A,
                                    const ushort* __restrict__ B,
                                    long ldA, long ldB, int K,
                                    f32x4 acc[4][4],
                                    ushort* ldsA, ushort* ldsB) {
  const int t = threadIdx.x;
  const int w = t >> 6, lane = t & 63;
  const int mrow = lane & 15, quad = lane >> 4;
  const int lr = lane >> 3;
  const int lc = ((lane & 7) ^ lr) * 8;     // pre-swizzled source column
  const int mh = (w & 1) * 64, nh = (w >> 1) * 64;
  for (int k0 = 0; k0 < K; k0 += 64) {
    __syncthreads();
    #pragma unroll
    for (int s = 0; s < 4; s++) {
      int row = w * 32 + s * 8 + lr;        // row&7 == lr
      glds16(&A[(long)row * ldA + k0 + lc], &ldsA[w * 2048 + s * 512]);
      glds16(&B[(long)row * ldB + k0 + lc], &ldsB[w * 2048 + s * 512]);
    }
    __syncthreads();
    #pragma unroll
    for (int kk = 0; kk < 2; kk++) {
      short8 av[4], bv[4];
      #pragma unroll
      for (int mi = 0; mi < 4; mi++)
        av[mi] = *(const short8*)&ldsA[(mh + mi * 16 + mrow) * 64 +
                                       ((kk * 32 + quad * 8) ^ ((mrow & 7) << 3))];
      #pragma unroll
      for (int ni = 0; ni < 4; ni++)
        bv[ni] = *(const short8*)&ldsB[(nh + ni * 16 + mrow) * 64 +
                                       ((kk * 32 + quad * 8) ^ ((mrow & 7) << 3))];
      #pragma unroll
      for (int mi = 0; mi < 4; mi++)
        #pragma unroll
        for (int ni = 0; ni < 4; ni++)
          acc[mi][ni] = __builtin_amdgcn_mfma_f32_16x16x32_bf16(av[mi], bv[ni], acc[mi][ni], 0, 0, 0);
    }
  }
}

// ---------------------------------------------------------------------------
// scores (256 thr): E[bz,j,i] = exp((dot+sq+sid+bias)*maskT).
// Partial row-sums of E -> ps. Two-pass epilogue (exp chains overlap).
// ---------------------------------------------------------------------------
__global__ __launch_bounds__(256) void k_scores(const ushort* __restrict__ Uq,
                                                const ushort* __restrict__ Uidw,
                                                const float* __restrict__ s_id,
                                                const float* __restrict__ s_q,
                                                const float* __restrict__ Wcb,
                                                const ushort* __restrict__ maskT,
                                                ushort* __restrict__ St,
                                                float* __restrict__ ps, int b0) {
  __shared__ ushort lds[16384];             // 32KB: gemm A|B, then S-tile
  ushort* ldsA = lds;
  ushort* ldsB = lds + 8192;
  int bz = blockIdx.z, b = b0 + bz;
  int m0 = blockIdx.x * 128;   // j
  int n0 = blockIdx.y * 128;   // i
  int tile_i = blockIdx.y;
  const ushort* A = Uq   + (long)b * L * E + (long)m0 * E;
  const ushort* B = Uidw + (long)b * L * E + (long)n0 * E;
  f32x4 acc[4][4] = {};
  gemm128_loop(A, B, E, E, E, acc, ldsA, ldsB);
  float bias = bf2f(f2bf(Wcb[0]));
  const int t = threadIdx.x, w = t >> 6, lane = t & 63;
  const int col = lane & 15, quad = lane >> 4;
  const int mh = (w & 1) * 64, nh = (w >> 1) * 64;

  __syncthreads();                          // done with gemm LDS
  float sidv[4];
  #pragma unroll
  for (int ni = 0; ni < 4; ni++)
    sidv[ni] = s_id[b * L + n0 + nh + ni * 16 + col];
  #pragma unroll
  for (int mi = 0; mi < 4; mi++) {
    float sqv[4];
    #pragma unroll
    for (int rg = 0; rg < 4; rg++)
      sqv[rg] = s_q[b * L + m0 + mh + mi * 16 + quad * 4 + rg];
    #pragma unroll
    for (int ni = 0; ni < 4; ni++) {
      int cl = nh + ni * 16 + col;
      #pragma unroll
      for (int rg = 0; rg < 4; rg++) {
        int row = mh + mi * 16 + quad * 4 + rg;
        float v = acc[mi][ni][rg] + sqv[rg] + sidv[ni] + bias;
        lds[row * 128 + (cl ^ ((row & 7) << 3))] = f2bf(v);
      }
    }
  }
  __syncthreads();
  ushort oall[64];
  // pass 1: exp + stats (all chains independent, overlap freely)
  #pragma unroll
  for (int p = 0; p < 8; p++) {
    int r2 = p * 16 + (t >> 4);
    int cu = (t & 15) * 8;
    uint4 sv = *(const uint4*)&lds[r2 * 128 + (cu ^ ((r2 & 7) << 3))];
    int jg = m0 + r2;
    uint4 mv = *(const uint4*)&maskT[(long)jg * L + n0 + cu];
    float lsum = 0.f;
    const ushort* sp = (const ushort*)&sv;
    const ushort* mp = (const ushort*)&mv;
    #pragma unroll
    for (int k = 0; k < 8; k++) {
      float ev = __expf(bf2f(sp[k]) * bf2f(mp[k]));
      oall[p * 8 + k] = f2bf(ev);
      lsum += ev;
    }
    #pragma unroll
    for (int off = 8; off >= 1; off >>= 1) lsum += __shfl_xor(lsum, off, 64);
    if ((t & 15) == 0) {
      ps[((long)bz * L + jg) * 16 + tile_i] = lsum;
    }
  }
  // pass 2: independent coalesced stores
  #pragma unroll
  for (int p = 0; p < 8; p++) {
    int r2 = p * 16 + (t >> 4);
    int cu = (t & 15) * 8;
    int jg = m0 + r2;
    *(uint4*)&St[(long)bz * L * L + (long)jg * L + n0 + cu] = *(const uint4*)&oall[p * 8];
  }
}

// ---------------------------------------------------------------------------
// redstats: fold 16 per-tile partial sums -> lg = 1/rowsum.
// ---------------------------------------------------------------------------
__global__ __launch_bounds__(256) void k_redstats(const float* __restrict__ ps,
                                                  float* __restrict__ lg) {
  int idx = blockIdx.x * 256 + threadIdx.x;   // 0 .. nb*L-1
  const float* psr = ps + (long)idx * 16;
  float s = 0.f;
  #pragma unroll
  for (int k = 0; k < 16; k++) s += psr[k];
  lg[idx] = 1.0f / s;
}

// ---------------------------------------------------------------------------
// scaleUq: UqS[b,e,j] = lg[j] * UqT[b,e,j]  (moves the lg factor to the
// B-operand of gemm_A so its A-staging is a pure bit-pack of raw E).
// ---------------------------------------------------------------------------
__global__ __launch_bounds__(256) void k_scaleUq(const ushort* __restrict__ UqT,
                                                 const float* __restrict__ lg,
                                                 ushort* __restrict__ UqS, int b0) {
  int bz = blockIdx.y, b = b0 + bz;
  long base = (long)blockIdx.x * 2048 + threadIdx.x * 8;   // within E*L
  int j = (int)(base & (L - 1));
  uint4 v = *(const uint4*)&UqT[(long)b * E * L + base];
  const ushort* p = (const ushort*)&v;
  ushort o[8];
  #pragma unroll
  for (int k = 0; k < 8; k++) o[k] = f2bf(bf2f(p[k]) * lg[bz * L + j + k]);
  *(uint4*)&UqS[(long)b * E * L + base] = *(const uint4*)&o[0];
}

// ---------------------------------------------------------------------------
// 64x64 NT/NT K-loop: BK=64, glds16, XOR chunk-swizzle, DOUBLE-BUF.
// ---------------------------------------------------------------------------
__device__ inline void gemm64x64_dbuf(const ushort* __restrict__ A,
                                      const ushort* __restrict__ B,
                                      long ldA, long ldB, int K,
                                      f32x4 acc[2][2],
                                      ushort* ldsA, ushort* ldsB) {
  const int t = threadIdx.x;
  const int w = t >> 6, lane = t & 63;
  const int mrow = lane & 15, quad = lane >> 4;
  const int lr = lane >> 3;
  const int lc = ((lane & 7) ^ lr) * 8;     // pre-swizzled source column
  const int mh = (w & 1) * 32, nh = (w >> 1) * 32;
  #pragma unroll
  for (int s = 0; s < 2; s++) {
    int row = w * 16 + s * 8 + lr;          // row&7 == lr
    glds16(&A[(long)row * ldA + lc], &ldsA[w * 1024 + s * 512]);
    glds16(&B[(long)row * ldB + lc], &ldsB[w * 1024 + s * 512]);
  }
  int cur = 0;
  for (int k0 = 0; k0 < K; k0 += 64) {
    __syncthreads();                        // buf[cur] staged; prev reads done
    int nxt = cur ^ 1;
    if (k0 + 64 < K) {                      // issue next-tile loads NOW
      #pragma unroll
      for (int s = 0; s < 2; s++) {
        int row = w * 16 + s * 8 + lr;
        glds16(&A[(long)row * ldA + k0 + 64 + lc], &ldsA[nxt * 4096 + w * 1024 + s * 512]);
        glds16(&B[(long)row * ldB + k0 + 64 + lc], &ldsB[nxt * 4096 + w * 1024 + s * 512]);
      }
    }
    const ushort* cA = &ldsA[cur * 4096];
    const ushort* cB = &ldsB[cur * 4096];
    #pragma unroll
    for (int kk = 0; kk < 2; kk++) {
      short8 av[2], bv[2];
      #pragma unroll
      for (int mi = 0; mi < 2; mi++)
        av[mi] = *(const short8*)&cA[(mh + mi * 16 + mrow) * 64 +
                                     ((kk * 32 + quad * 8) ^ ((mrow & 7) << 3))];
      #pragma unroll
      for (int ni = 0; ni < 2; ni++)
        bv[ni] = *(const short8*)&cB[(nh + ni * 16 + mrow) * 64 +
                                     ((kk * 32 + quad * 8) ^ ((mrow & 7) << 3))];
      #pragma unroll
      for (int mi = 0; mi < 2; mi++)
        #pragma unroll
        for (int ni = 0; ni < 2; ni++)
          acc[mi][ni] = __builtin_amdgcn_mfma_f32_16x16x32_bf16(av[mi], bv[ni], acc[mi][ni], 0, 0, 0);
    }
    cur = nxt;
  }
}

// ---------------------------------------------------------------------------
// gemm_Tt (64x64): Tt[b,e,j] = lg[j]^2 * sum_i UidT[b,e,i] * E[bz,j,i]
// (the SECOND lg factor — the one gemm_A used to apply — is folded here)
// ---------------------------------------------------------------------------
__global__ __launch_bounds__(256) void k_gemm_Tt(const ushort* __restrict__ UidT,
                                                 const ushort* __restrict__ Et,
                                                 const float* __restrict__ lg,
                                                 ushort* __restrict__ Tt, int b0) {
  __shared__ ushort lds[16384];             // 32KB: A 2x4096 | B 2x4096
  ushort* ldsA = lds;
  ushort* ldsB = lds + 8192;
  int bz = blockIdx.z, b = b0 + bz;
  int e0 = (blockIdx.x & 1) * 64;        // e tile
  int j0 = (blockIdx.x >> 1) * 64;       // j tile
  const ushort* A = UidT + (long)b * E * L + (long)e0 * L;
  const ushort* B = Et   + (long)bz * L * L + (long)j0 * L;
  f32x4 acc[2][2] = {};
  gemm64x64_dbuf(A, B, L, L, L, acc, ldsA, ldsB);
  const int t = threadIdx.x, w = t >> 6, lane = t & 63;
  const int col = lane & 15, quad = lane >> 4;
  const int mh = (w & 1) * 32, nh = (w >> 1) * 32;
  __syncthreads();
  #pragma unroll
  for (int mi = 0; mi < 2; mi++)
    #pragma unroll
    for (int ni = 0; ni < 2; ni++) {
      int cl = nh + ni * 16 + col;
      float scv = lg[(long)bz * L + j0 + cl];
      float sc = scv * scv;
      #pragma unroll
      for (int rg = 0; rg < 4; rg++) {
        int row = mh + mi * 16 + quad * 4 + rg;      // e-local 0..63
        lds[row * 64 + (cl ^ ((row & 7) << 3))] = f2bf(acc[mi][ni][rg] * sc);
      }
    }
  __syncthreads();
  #pragma unroll
  for (int p = 0; p < 2; p++) {
    int r2 = p * 32 + (t >> 3);
    int cu = (t & 7) * 8;
    uint4 v = *(const uint4*)&lds[r2 * 64 + (cu ^ ((r2 & 7) << 3))];
    *(uint4*)&Tt[(long)b * E * L + (long)(e0 + r2) * L + j0 + cu] = v;
  }
}

// ---------------------------------------------------------------------------
// gemm_A (64x128), 512 threads / 8 waves (wave tile 32x32).
// A-operand = RAW E[j,i] staged transposed as a pure bit-pack (lg folded
// into UqS / Tt on the B side). B glds16 double-buffered; E reg-prefetch.
// ---------------------------------------------------------------------------
__global__ __launch_bounds__(512) void k_gemm_A(const ushort* __restrict__ Et,
                                                const ushort* __restrict__ UqS,
                                                const ushort* __restrict__ Tt,
                                                const ushort* __restrict__ UidB,
                                                float* __restrict__ out, int b0) {
  __shared__ ushort ldsA[2 * 4608];         // 18 KB, transposed+swizzled A
  __shared__ ushort ldsB[2 * 8192];         // 32 KB
  int bz = blockIdx.z, b = b0 + bz;
  int m0 = blockIdx.x * 64;    // i
  int n0 = blockIdx.y * 128;   // c base: 0 -> Uq, 128 -> T
  const ushort* Eb = Et + (long)bz * L * L + m0;   // row j: Eb[j*L + il]
  const ushort* B = (blockIdx.y == 0) ? (UqS + (long)b * E * L)
                                      : (Tt  + (long)b * E * L);
  const int t = threadIdx.x, w = t >> 6, lane = t & 63;
  const int mrow = lane & 15, quad = lane >> 4;
  const int lr = lane >> 3;
  const int lc = ((lane & 7) ^ lr) * 8;
  const int mh = (w & 1) * 32, nh = (w >> 1) * 32;   // 2m x 4n wave grid
  const int jp2 = (t >> 4) * 2;   // j pair base 0..62
  const int ic  = (t & 15) * 4;   // i chunk (4 ushorts)
  f32x4 acc[2][2] = {};
  // prologue: stage k0 = 0 into buf 0
  uint2 q0 = *(const uint2*)&Eb[(long)jp2 * L + ic];
  uint2 q1 = *(const uint2*)&Eb[(long)(jp2 + 1) * L + ic];
  #pragma unroll
  for (int s = 0; s < 2; s++) {
    int row = w * 16 + s * 8 + lr;          // 0..127, row&7 == lr
    glds16(&B[(long)row * L + lc], &ldsB[w * 1024 + s * 512]);
  }
  {
    const ushort* p0 = (const ushort*)&q0;
    const ushort* p1 = (const ushort*)&q1;
    #pragma unroll
    for (int k = 0; k < 4; k++) {
      u32 pk = (u32)p0[k] | ((u32)p1[k] << 16);
      int i = ic + k;
      int cs = jp2 ^ (((i >> 3) & 7) << 3);
      *(u32*)&ldsA[i * 72 + cs] = pk;
    }
  }
  // reg-prefetch k0 = 64
  q0 = *(const uint2*)&Eb[(long)(64 + jp2) * L + ic];
  q1 = *(const uint2*)&Eb[(long)(64 + jp2 + 1) * L + ic];

  int cur = 0;
  for (int k0 = 0; k0 < L; k0 += 64) {
    __syncthreads();                        // buf[cur] ready; q regs landed
    int nxt = cur ^ 1;
    if (k0 + 64 < L) {
      #pragma unroll
      for (int s = 0; s < 2; s++) {
        int row = w * 16 + s * 8 + lr;
        glds16(&B[(long)row * L + k0 + 64 + lc], &ldsB[nxt * 8192 + w * 1024 + s * 512]);
      }
      const ushort* p0 = (const ushort*)&q0;
      const ushort* p1 = (const ushort*)&q1;
      #pragma unroll
      for (int k = 0; k < 4; k++) {
        u32 pk = (u32)p0[k] | ((u32)p1[k] << 16);
        int i = ic + k;
        int cs = jp2 ^ (((i >> 3) & 7) << 3);
        *(u32*)&ldsA[nxt * 4608 + i * 72 + cs] = pk;
      }
    }
    // reg-prefetch k0+128 (lands during this and next compute phase)
    if (k0 + 128 < L) {
      q0 = *(const uint2*)&Eb[(long)(k0 + 128 + jp2) * L + ic];
      q1 = *(const uint2*)&Eb[(long)(k0 + 128 + jp2 + 1) * L + ic];
    }
    const ushort* cA = &ldsA[cur * 4608];
    const ushort* cB = &ldsB[cur * 8192];
    #pragma unroll
    for (int kk = 0; kk < 2; kk++) {
      short8 av[2], bv[2];
      #pragma unroll
      for (int mi = 0; mi < 2; mi++) {
        int i = mh + mi * 16 + mrow;
        av[mi] = *(const short8*)&cA[i * 72 +
                   ((kk * 32 + quad * 8) ^ (((i >> 3) & 7) << 3))];
      }
      #pragma unroll
      for (int ni = 0; ni < 2; ni++)
        bv[ni] = *(const short8*)&cB[(nh + ni * 16 + mrow) * 64 +
                                     ((kk * 32 + quad * 8) ^ ((mrow & 7) << 3))];
      #pragma unroll
      for (int mi = 0; mi < 2; mi++)
        #pragma unroll
        for (int ni = 0; ni < 2; ni++)
          acc[mi][ni] = __builtin_amdgcn_mfma_f32_16x16x32_bf16(av[mi], bv[ni], acc[mi][ni], 0, 0, 0);
    }
    cur = nxt;
  }
  const int col = mrow;
  #pragma unroll
  for (int mi = 0; mi < 2; mi++)
    #pragma unroll
    for (int ni = 0; ni < 2; ni++)
      #pragma unroll
      for (int rg = 0; rg < 4; rg++) {
        int ig = m0 + mh + mi * 16 + quad * 4 + rg;
        int c  = n0 + nh + ni * 16 + col;
        float a = acc[mi][ni][rg];
        float uidf = bf2f(UidB[(long)b * L * E + (long)ig * E + (c & 127)]);
        long ob = ((long)b * L + ig) * 512;
        if (c < 128) {
          out[ob + c]       = uidf;        // Vid identity block
          out[ob + 128 + c] = a;           // A_D2Q
          out[ob + 256 + c] = uidf * a;    // Uid * A_D2Q
        } else {
          out[ob + 256 + c] = uidf * a;    // Uid * A_Q2D
        }
      }
}

// ---------------------------------------------------------------------------
extern "C" void kernel_launch(void* const* d_in, const int* in_sizes, int n_in,
                              void* d_out, int out_size, void* d_ws, size_t ws_size,
                              hipStream_t stream) {
  const float* Uq   = (const float*)d_in[0];
  const float* Uid  = (const float*)d_in[1];
  const float* mask = (const float*)d_in[2];
  const float* Wcw  = (const float*)d_in[3];
  const float* Wcb  = (const float*)d_in[4];
  float* out = (float*)d_out;

  char* ws = (char*)d_ws;
  size_t off = 0;
  auto alloc = [&](size_t bytes) -> void* {
    void* p = ws + off; off += (bytes + 255) & ~(size_t)255; return p;
  };
  const size_t nUb = (size_t)NB * L * E * 2;
  ushort* UqB   = (ushort*)alloc(nUb);
  ushort* UidB  = (ushort*)alloc(nUb);
  ushort* Uidw  = (ushort*)alloc(nUb);
  ushort* UqT   = (ushort*)alloc(nUb);
  ushort* UidT  = (ushort*)alloc(nUb);
  ushort* UqS   = (ushort*)alloc(nUb);
  ushort* Tt    = (ushort*)alloc(nUb);
  ushort* maskT = (ushort*)alloc((size_t)L * L * 2);
  float*  s_id  = (float*)alloc((size_t)NB * L * 4);
  float*  s_q   = (float*)alloc((size_t)NB * L * 4);
  float*  lg    = (float*)alloc((size_t)NB * L * 4);
  float*  ps    = (float*)alloc((size_t)NB * L * 16 * 4);
  // chunk: St only: nb_c * 8.4 MB
  const size_t per_batch = (size_t)L * L * 2;
  size_t avail = (ws_size > off + per_batch) ? (ws_size - off) : per_batch;
  int nb_c = (int)(avail / per_batch);
  if (nb_c < 1) nb_c = 1;
  if (nb_c > NB) nb_c = NB;
  ushort* St = (ushort*)(ws + off);                      // holds E = exp(S)

  dim3 tb(32, 8);
  k_prep2<<<NB * L / 64, 512, 0, stream>>>(Uq, Uid, Wcw, UqB, UidB, Uidw, UqT, UidT, s_id, s_q);
  k_maskT<<<dim3(L / 32, L / 32), tb, 0, stream>>>(mask, maskT);

  for (int b0 = 0; b0 < NB; b0 += nb_c) {
    int nb = (NB - b0 < nb_c) ? (NB - b0) : nb_c;
    k_scores<<<dim3(L / 128, L / 128, nb), 256, 0, stream>>>(UqB, Uidw, s_id, s_q, Wcb, maskT, St, ps, b0);
    k_redstats<<<dim3(nb * L / 256), 256, 0, stream>>>(ps, lg);
    k_scaleUq<<<dim3(E * L / 2048, nb), 256, 0, stream>>>(UqT, lg, UqS, b0);
    k_gemm_Tt<<<dim3(2 * (L / 64), 1, nb), 256, 0, stream>>>(UidT, St, lg, Tt, b0);
    k_gemm_A<<<dim3(L / 64, 2, nb), 512, 0, stream>>>(St, UqS, Tt, UidB, out, b0);
  }
}